// Round 3
// baseline (60.704 us; speedup 1.0000x reference)
//
#include <hip/hip_runtime.h>

// NeuralQuantizer: out[i] = nearest center to x[i], centers = linspace(-1,1,256).
// Closed form: idx = clamp(round((x+1)*127.5), 0, 255); q = -1 + idx*(2/255).
// Memory-bound elementwise: 2x 16B vectors per thread (8 floats), exact cover
// at 1024 blocks x 256 threads. Nontemporal stores (output never re-read).
// NOTE: use native ext_vector_type — __builtin_nontemporal_store rejects
// HIP_vector_type<float,4>.

typedef float vfloat4 __attribute__((ext_vector_type(4)));

__device__ __forceinline__ float quant1(float v) {
    float t = (v + 1.0f) * 127.5f;
    float idx = __builtin_rintf(t);
    idx = fminf(fmaxf(idx, 0.0f), 255.0f);
    return fmaf(idx, 2.0f / 255.0f, -1.0f);
}

__device__ __forceinline__ vfloat4 quant4(vfloat4 v) {
    vfloat4 o;
    o.x = quant1(v.x);
    o.y = quant1(v.y);
    o.z = quant1(v.z);
    o.w = quant1(v.w);
    return o;
}

__global__ __launch_bounds__(256) void quantize_f4x2(const vfloat4* __restrict__ x,
                                                     vfloat4* __restrict__ out,
                                                     int n4) {
    int i = 2 * (blockIdx.x * blockDim.x + threadIdx.x);
    if (i + 1 < n4) {
        vfloat4 v0 = x[i];
        vfloat4 v1 = x[i + 1];
        __builtin_nontemporal_store(quant4(v0), &out[i]);
        __builtin_nontemporal_store(quant4(v1), &out[i + 1]);
    } else if (i < n4) {
        __builtin_nontemporal_store(quant4(x[i]), &out[i]);
    }
}

extern "C" void kernel_launch(void* const* d_in, const int* in_sizes, int n_in,
                              void* d_out, int out_size, void* d_ws, size_t ws_size,
                              hipStream_t stream) {
    const vfloat4* x = (const vfloat4*)d_in[0];
    vfloat4* out = (vfloat4*)d_out;
    int n = in_sizes[0];            // 2,097,152 floats
    int n4 = n / 4;                 // 524,288 vectors
    int block = 256;
    int per_block = block * 2;      // two 16B vectors per thread
    int grid = (n4 + per_block - 1) / per_block;   // 1024 blocks
    quantize_f4x2<<<grid, block, 0, stream>>>(x, out, n4);
}